// Round 9
// baseline (612.394 us; speedup 1.0000x reference)
//
#include <hip/hip_runtime.h>

// NeuralAudioGraph: N=256, D=H=512, E=128, 4 heads, 3 GAT layers.
// r16: apply r15's lesson everywhere. Bankable rule from r8-r15: per-thread
// K-iteration global load-use loops serialize at ~460cyc/load on this compiler
// (k_ef fixed by all-LDS inner loop; 488->458, k_ef left top-5). k_uv (43us,
// VALUBusy 27%) and structurally-identical k_s (x3), k_op, k_op2 have the same
// disease: 512 serialized W loads/thread. Fix: cooperative k-tiled LDS staging
// (64k x 256col = 64KB W tile, coalesced float4, barrier, inner loop all-LDS).
// Same accumulation expressions & k-order -> bit-identical. k_s widened to
// 8 rows/block (halves W L2 re-reads; runs 3x). Baseline r15: 458us.

typedef __attribute__((ext_vector_type(8))) short short8;   // 8 x bf16 (MFMA frag)
typedef __attribute__((ext_vector_type(4))) float f32x4;    // MFMA accumulator
typedef unsigned short u16;
typedef unsigned int u32;

__device__ __forceinline__ float bf2f(u16 h) { return __uint_as_float(((u32)h) << 16); }
__device__ __forceinline__ u16 f2bf(float f) {
  u32 u = __float_as_uint(f);
  u += 0x7fffu + ((u >> 16) & 1u);   // round-to-nearest-even
  return (u16)(u >> 16);
}
__device__ __forceinline__ float lrelu(float v) { return fmaxf(v, 0.2f * v); }
__device__ __forceinline__ float ldany(int f32mode, const void* p, int i) {
  return f32mode ? ((const float*)p)[i] : bf2f(((const u16*)p)[i]);
}

// ---------------- dtype detector ----------------------------------------------------
__global__ __launch_bounds__(256) void k_detect(const u16* emb, int* flag) {
  bool big = false;
  for (int i = blockIdx.x * 256 + threadIdx.x; i < 131072; i += 256 * 64) {
    float v = bf2f(emb[i]);
    big |= !(fabsf(v) <= 1e6f);
  }
  unsigned long long m = __ballot(big);
  if (m && (threadIdx.x & 63) == 0) atomicOr(flag, 1);
}

// ---------------- small-vector ingest -> canonical f32 ------------------------------
struct VD { const void* src; int dst, n; };
struct VArgs { VD v[16]; };
__global__ __launch_bounds__(256) void k_vec(VArgs a, const int* flag, float* out) {
  int f = *flag;
  VD d = a.v[blockIdx.x];
  for (int i = threadIdx.x; i < d.n; i += 256)
    out[d.dst + i] = ldany(f, d.src, i);
}

// ---------------- big-matrix ingest -> canonical f32 --------------------------------
struct CArgs { const void* src[7]; float* dst[7]; int n[7]; };
__global__ __launch_bounds__(256) void k_cvt(CArgs a, const int* flag) {
  int f = *flag;
  int e = blockIdx.y;
  const void* s = a.src[e];
  float* d = a.dst[e];
  int n = a.n[e];
  for (int i = blockIdx.x * 256 + threadIdx.x; i < n; i += 2048 * 256)
    d[i] = ldany(f, s, i);
}

// ---------------- ef_w2 f32 [512][128] -> bf16 MFMA-fragment-linear -----------------
// w2fr[(kc*8+nt)*512 + l*8 + e] = bf16(w2[c = kc*32+(l>>4)*8+e][n = nt*16+(l&15)])
__global__ __launch_bounds__(256) void k_w2tb(const float* efw2f, u16* w2fr) {
  int idx = blockIdx.x * 256 + threadIdx.x;   // 65536
  int e = idx & 7, l = (idx >> 3) & 63, nt = (idx >> 9) & 7, kc = idx >> 12;
  int n = nt * 16 + (l & 15);
  int c = kc * 32 + ((l >> 4) << 3) + e;
  w2fr[idx] = f2bf(efw2f[c * 128 + n]);
}

// ---------------- V rows -> f32 MFMA-fragment-linear --------------------------------
// vfrag[jb*8192 + kc*512 + l*8 + e] = V[jb*16+(l&15)][kc*32+(l>>4)*8+e]
__global__ __launch_bounds__(256) void k_vfr(const float* uvf, float* vfrag) {
  const float* V = uvf + 393216;
  int idx = blockIdx.x * 256 + threadIdx.x;   // grid 512 -> 131072
  int e = idx & 7, l = (idx >> 3) & 63, kc = (idx >> 9) & 15, jb = idx >> 13;
  int j = jb * 16 + (l & 15);
  int c = kc * 32 + ((l >> 4) << 3) + e;
  vfrag[idx] = V[j * 512 + c];
}

// ---------------- U/V = emb @ W1 halves; f64 for ep (arr 0,1), f32 for ef -----------
// grid (2, 64, 4), 256 thr. LDS-staged: W k-tile 64x256 (64KB) + 4 emb rows (8KB).
// Inner loop all-LDS; same accumulation expressions & k-order -> bit-identical.
__global__ __launch_bounds__(256) void k_uv(const float* embf, const float* epw1f,
    const float* efw1f, const float* vecf, float* uvf) {
  __shared__ float wS[16384];   // 64 KB: [row 0..63][col 0..255]
  __shared__ float eS[2048];    // 8 KB: 4 rows x 512
  int tid = threadIdx.x;
  int col = blockIdx.x * 256 + tid;
  int r0 = blockIdx.y * 4;
  int arr = blockIdx.z;
  const float* Wb = ((arr < 2) ? epw1f : efw1f) + (arr & 1) * 262144 + blockIdx.x * 256;
  const float* e = embf + r0 * 512;
  float bias = (arr == 1) ? vecf[col] : (arr == 3) ? vecf[2064 + col] : 0.f;
  float* outp = uvf + arr * 131072 + r0 * 512 + col;

  for (int q = tid; q < 512; q += 256)
    *(float4*)(eS + q * 4) = *(const float4*)(e + q * 4);

  if (arr < 2) {
    double a0 = 0.0, a1 = 0.0, a2 = 0.0, a3 = 0.0;
    for (int kt = 0; kt < 8; ++kt) {
      __syncthreads();
      for (int q = tid; q < 4096; q += 256) {
        int row = q >> 6, c4 = q & 63;
        *(float4*)(wS + row * 256 + c4 * 4) =
            *(const float4*)(Wb + (kt * 64 + row) * 512 + c4 * 4);
      }
      __syncthreads();
      for (int kk = 0; kk < 64; kk += 2) {
        int k = kt * 64 + kk;
        double w0 = (double)wS[kk * 256 + tid];
        double w1 = (double)wS[(kk + 1) * 256 + tid];
        float2 e0 = *(const float2*)(eS + k);
        float2 e1 = *(const float2*)(eS + 512 + k);
        float2 e2 = *(const float2*)(eS + 1024 + k);
        float2 e3 = *(const float2*)(eS + 1536 + k);
        a0 += (double)e0.x * w0 + (double)e0.y * w1;
        a1 += (double)e1.x * w0 + (double)e1.y * w1;
        a2 += (double)e2.x * w0 + (double)e2.y * w1;
        a3 += (double)e3.x * w0 + (double)e3.y * w1;
      }
    }
    outp[0]    = (float)(a0 + (double)bias);
    outp[512]  = (float)(a1 + (double)bias);
    outp[1024] = (float)(a2 + (double)bias);
    outp[1536] = (float)(a3 + (double)bias);
  } else {
    float a0 = 0.f, a1 = 0.f, a2 = 0.f, a3 = 0.f;
    for (int kt = 0; kt < 8; ++kt) {
      __syncthreads();
      for (int q = tid; q < 4096; q += 256) {
        int row = q >> 6, c4 = q & 63;
        *(float4*)(wS + row * 256 + c4 * 4) =
            *(const float4*)(Wb + (kt * 64 + row) * 512 + c4 * 4);
      }
      __syncthreads();
      for (int kk = 0; kk < 64; kk += 2) {
        int k = kt * 64 + kk;
        float w0 = wS[kk * 256 + tid];
        float w1 = wS[(kk + 1) * 256 + tid];
        float2 e0 = *(const float2*)(eS + k);
        float2 e1 = *(const float2*)(eS + 512 + k);
        float2 e2 = *(const float2*)(eS + 1024 + k);
        float2 e3 = *(const float2*)(eS + 1536 + k);
        a0 = fmaf(e0.x, w0, fmaf(e0.y, w1, a0));
        a1 = fmaf(e1.x, w0, fmaf(e1.y, w1, a1));
        a2 = fmaf(e2.x, w0, fmaf(e2.y, w1, a2));
        a3 = fmaf(e3.x, w0, fmaf(e3.y, w1, a3));
      }
    }
    outp[0]    = a0 + bias;
    outp[512]  = a1 + bias;
    outp[1024] = a2 + bias;
    outp[1536] = a3 + bias;
  }
}

// ---------------- f64 row sums / sums-of-squares ------------------------------------
__global__ __launch_bounds__(64) void k_stats64(const float* uvf, double* sums, double* sumsq) {
  int bid = blockIdx.x;           // arr*256 + row
  int lane = threadIdx.x;
  const float* p = uvf + bid * 512;
  double s = 0.0, s2 = 0.0;
  for (int q = lane; q < 512; q += 64) { double v = p[q]; s += v; s2 += v * v; }
#pragma unroll
  for (int m = 1; m < 64; m <<= 1) { s += __shfl_xor(s, m, 64); s2 += __shfl_xor(s2, m, 64); }
  if (lane == 0) { sums[bid] = s; sumsq[bid] = s2; }
}

// ---------------- cross[i][j] = U_i . V_j (f64): z=0 -> ep, z=1 -> ef ---------------
__global__ __launch_bounds__(256) void k_cross(const float* uvf, double* crossep,
                                               double* crossef) {
  __shared__ float Uc[16][132], Vc[16][132];
  int z = blockIdx.z;
  const float* U = uvf + z * 262144;
  const float* V = U + 131072;
  double* out = z ? crossef : crossep;
  int tid = threadIdx.x, ti = tid & 15, tj = tid >> 4;
  int i0 = blockIdx.y * 16, j0 = blockIdx.x * 16;
  double acc = 0.0;
  for (int c0 = 0; c0 < 512; c0 += 128) {
    __syncthreads();
    for (int idx = tid; idx < 2048; idx += 256) {
      int r = idx >> 7, c = idx & 127;
      Uc[r][c] = U[(i0 + r) * 512 + c0 + c];
      Vc[r][c] = V[(j0 + r) * 512 + c0 + c];
    }
    __syncthreads();
#pragma unroll
    for (int c4 = 0; c4 < 128; c4 += 4) {
      float4 uu = *(const float4*)&Uc[ti][c4];
      float4 vv = *(const float4*)&Vc[tj][c4];
      float p = fmaf(uu.x, vv.x, fmaf(uu.y, vv.y, fmaf(uu.z, vv.z, uu.w * vv.w)));
      acc += (double)p;
    }
  }
  out[(i0 + ti) * 256 + j0 + tj] = acc;
}

// ---------------- edge predictor, stats-based tiled (1 thread / pair) ---------------
__global__ __launch_bounds__(256) void k_ep_t(const float* uvf, const double* sums,
    const double* sumsq, const double* crossep, const float* vecf,
    float* act, float* maskv) {
  __shared__ float Uc[16][132], Vc[16][132];
  int tid = threadIdx.x, ti = tid & 15, tj = tid >> 4;
  int i0 = blockIdx.y * 16, j0 = blockIdx.x * 16;
  int i = i0 + ti, j = j0 + tj;
  double md = (sums[i] + sums[256 + j]) * (1.0 / 512.0);
  double qd = (sumsq[i] + 2.0 * crossep[i * 256 + j] + sumsq[256 + j]) * (1.0 / 512.0);
  float iv = (float)(1.0 / sqrt(qd - md * md + 1e-5));
  float bb = (float)(-md) * iv;
  const float* U = uvf;
  const float* V = uvf + 131072;
  const float* g_ = vecf + 512;
  const float* be_ = vecf + 1024;
  const float* w2_ = vecf + 1536;
  double acc = 0.0;
  for (int c0 = 0; c0 < 512; c0 += 128) {
    __syncthreads();
    for (int idx = tid; idx < 2048; idx += 256) {
      int r = idx >> 7, c = idx & 127;
      Uc[r][c] = U[(i0 + r) * 512 + c0 + c];
      Vc[r][c] = V[(j0 + r) * 512 + c0 + c];
    }
    __syncthreads();
#pragma unroll
    for (int c4 = 0; c4 < 128; c4 += 4) {
      float4 uu = *(const float4*)&Uc[ti][c4];
      float4 vv = *(const float4*)&Vc[tj][c4];
      float4 gg = *(const float4*)(g_ + c0 + c4);
      float4 b4 = *(const float4*)(be_ + c0 + c4);
      float4 w4 = *(const float4*)(w2_ + c0 + c4);
      float z, s4 = 0.f;
      z = fmaf(fmaf(uu.x + vv.x, iv, bb), gg.x, b4.x); s4 = fmaf(lrelu(z), w4.x, s4);
      z = fmaf(fmaf(uu.y + vv.y, iv, bb), gg.y, b4.y); s4 = fmaf(lrelu(z), w4.y, s4);
      z = fmaf(fmaf(uu.z + vv.z, iv, bb), gg.z, b4.z); s4 = fmaf(lrelu(z), w4.z, s4);
      z = fmaf(fmaf(uu.w + vv.w, iv, bb), gg.w, b4.w); s4 = fmaf(lrelu(z), w4.w, s4);
      acc += (double)s4;
    }
  }
  double logit = acc + (double)vecf[2048];
  bool a = (logit > 0.0) && (i != j);
  act[i * 256 + j] = a ? 1.0f : 0.0f;
  maskv[j * 256 + i] = (a || i == j) ? 0.f : -1e9f;         // adj[dst][src] mask
}

// ---------------- edge features: all-LDS inner loop + bf16 MFMA (r15, validated) ----
__global__ __launch_bounds__(512, 2) void k_ef(const float* uvf, const double* sums,
    const double* sumsq, const double* crossef, const float* vecf,
    const u16* w2fr, const float* vfrag, float* ef_f) {
  __shared__ u16 w2S[16384];                 // 32 KB: 4 kc x 8 nt x 512
  __shared__ float vS0[4096], vS1[4096];     // 16+16 KB
  __shared__ float uS[8192];                 // 32 KB: 16 rows x 512
  __shared__ float gS[512], beS[512];        // 4 KB
  int tid = threadIdx.x;
  int lane = tid & 63, w = tid >> 6;         // w 0..7
  int bx = blockIdx.x;
  int bi = bx >> 4, bj = bx & 15;
  int i0 = bi * 16;
  int iA = i0 + w * 2, iB = iA + 1;
  int l15 = lane & 15;
  int j = bj * 16 + l15;
  int ksl = (lane >> 4) * 8;

  double sj = sums[768 + j], s2j = sumsq[768 + j];
  double mA = (sums[512 + iA] + sj) * (1.0 / 512.0);
  double qA = (sumsq[512 + iA] + 2.0 * crossef[iA * 256 + j] + s2j) * (1.0 / 512.0);
  float ivA = (float)(1.0 / sqrt(qA - mA * mA + 1e-5));
  float bbA = (float)(-mA) * ivA;
  double mB = (sums[512 + iB] + sj) * (1.0 / 512.0);
  double qB = (sumsq[512 + iB] + 2.0 * crossef[iB * 256 + j] + s2j) * (1.0 / 512.0);
  float ivB = (float)(1.0 / sqrt(qB - mB * mB + 1e-5));
  float bbB = (float)(-mB) * ivB;

  const float* Vg = vfrag + bj * 8192;
  for (int q = tid; q < 2048; q += 512) {
    float4 v = *(const float4*)(Vg + q * 4);
    int kc = q >> 7, r = q & 127, ln = r >> 1;
    if (r & 1) *(float4*)(vS1 + kc * 256 + ln * 4) = v;
    else       *(float4*)(vS0 + kc * 256 + ln * 4) = v;
  }
  const float* Ug = uvf + 262144 + i0 * 512;
  for (int q = tid; q < 2048; q += 512)
    *(float4*)(uS + q * 4) = *(const float4*)(Ug + q * 4);
  if (tid < 128)      *(float4*)(gS + tid * 4)  = *(const float4*)(vecf + 2576 + tid * 4);
  else if (tid < 256) *(float4*)(beS + (tid - 128) * 4) = *(const float4*)(vecf + 3088 + (tid - 128) * 4);

  f32x4 acc[2][8];
#pragma unroll
  for (int ai = 0; ai < 2; ++ai)
#pragma unroll
    for (int bq = 0; bq < 8; ++bq) acc[ai][bq] = (f32x4){0.f, 0.f, 0.f, 0.f};

  auto H8 = [&](float4 u0, float4 u1, float4 v0, float4 v1, float4 g0, float4 g1,
                float4 e0, float4 e1, float iv, float bb) -> short8 {
    short8 a; float z;
    z = fmaf(u0.x + v0.x, iv, bb); z = fmaf(z, g0.x, e0.x); a[0] = (short)f2bf(lrelu(z));
    z = fmaf(u0.y + v0.y, iv, bb); z = fmaf(z, g0.y, e0.y); a[1] = (short)f2bf(lrelu(z));
    z = fmaf(u0.z + v0.z, iv, bb); z = fmaf(z, g0.z, e0.z); a[2] = (short)f2bf(lrelu(z));
    z = fmaf(u0.w + v0.w, iv, bb); z = fmaf(z, g0.w, e0.w); a[3] = (short)f2bf(lrelu(z));
    z = fmaf(u1.x + v1.x, iv, bb); z = fmaf(z, g1.x, e1.x); a[4] = (short)f2bf(lrelu(z));
    z = fmaf(u1.y + v1.y, iv, bb); z = fmaf(z, g1.y, e1.y); a[5] = (short)f2bf(lrelu(z));
    z = fmaf(u1.z + v1.z, iv, bb); z = fmaf(z, g1.z, e1.z); a[6] = (short)f2bf(lrelu(z));
    z = fmaf(u1.w + v1.w, iv, bb); z = fmaf(z, g1.w, e1.w); a[7] = (short)f2bf(lrelu(z));
    return a;
  };

  const float* uA = uS + (w * 2) * 512;
  const float* uB = uA + 512;

  for (int kq = 0; kq < 4; ++kq) {
    __syncthreads();
    const short8* src = (const short8*)(w2fr + kq * 16384);
    for (int q = tid; q < 2048; q += 512)
      *(short8*)(w2S + q * 8) = src[q];
    __syncthreads();
#pragma unroll
    for (int kk = 0; kk < 4; ++kk) {
      int kc = kq * 4 + kk;
      int k0 = kc * 32 + ksl;
      float4 u0 = *(const float4*)(uA + k0);
      float4 u1 = *(const float4*)(uA + k0 + 4);
      float4 b0 = *(const float4*)(uB + k0);
      float4 b1 = *(const float4*)(uB + k0 + 4);
      float4 v0 = *(const float4*)(vS0 + kc * 256 + lane * 4);
      float4 v1 = *(const float4*)(vS1 + kc * 256 + lane * 4);
      float4 g0 = *(const float4*)(gS + k0);
      float4 g1 = *(const float4*)(gS + k0 + 4);
      float4 e0 = *(const float4*)(beS + k0);
      float4 e1 = *(const float4*)(beS + k0 + 4);
      short8 aA = H8(u0, u1, v0, v1, g0, g1, e0, e1, ivA, bbA);
      short8 aB = H8(b0, b1, v0, v1, g0, g1, e0, e1, ivB, bbB);
#pragma unroll
      for (int nt = 0; nt < 8; ++nt) {
        short8 bv = *(const short8*)(w2S + kk * 4096 + nt * 512 + lane * 8);
        acc[0][nt] = __builtin_amdgcn_mfma_f32_16x16x32_bf16(aA, bv, acc[0][nt], 0, 0, 0);
        acc[1][nt] = __builtin_amdgcn_mfma_f32_16x16x32_bf16(aB, bv, acc[1][nt], 0, 0, 0);
      }
    }
  }
#pragma unroll
  for (int mi = 0; mi < 2; ++mi) {
    int ii = mi ? iB : iA;
#pragma unroll
    for (int nt = 0; nt < 8; ++nt) {
      int n = nt * 16 + l15;
      float bias = vecf[3600 + n];
#pragma unroll
      for (int r = 0; r < 4; ++r) {
        int row = (lane >> 4) * 4 + r;
        ef_f[(ii * 256 + bj * 16 + row) * 128 + n] = acc[mi][nt][r] + bias;
      }
    }
  }
}

// ---------------- GAT s = x @ W[l]; LDS-staged, 8 rows/block ------------------------
// grid (8, 32), 256 thr. W tile 64x256 (64KB) + 8 x-rows (16KB). Same fmaf
// expression & k-order as before -> bit-identical.
__global__ __launch_bounds__(256) void k_s(const float* x, const float* Wf, float* sf) {
  __shared__ float wS[16384];   // 64 KB
  __shared__ float eS[4096];    // 16 KB: 8 rows x 512
  int tid = threadIdx.x;
  int hcb = blockIdx.x * 256;   // grid.x = 8
  int n0 = blockIdx.y * 8;      // grid.y = 32
  const float* xr = x + n0 * 512;
  for (int q = tid; q < 1024; q += 256)
    *(float4*)(eS + q * 4) = *(const float4*)(xr + q * 4);
  float a[8] = {0.f, 0.f, 0.f, 0.f, 0.f, 0.f, 0.f, 0.f};
  for (int kt = 0; kt < 8; ++kt) {
    __syncthreads();
    for (int q = tid; q < 4096; q += 256) {
      int row = q >> 6, c4 = q & 63;
      *(float4*)(wS + row * 256 + c4 * 4) =
          *(const float4*)(Wf + (kt * 64 + row) * 2048 + hcb + c4 * 4);
    }
    __syncthreads();
    for (int kk = 0; kk < 64; kk += 2) {
      int k = kt * 64 + kk;
      float w0 = wS[kk * 256 + tid];
      float w1 = wS[(kk + 1) * 256 + tid];
#pragma unroll
      for (int r = 0; r < 8; ++r) {
        float2 e = *(const float2*)(eS + r * 512 + k);
        a[r] = fmaf(e.x, w0, fmaf(e.y, w1, a[r]));
      }
    }
  }
#pragma unroll
  for (int r = 0; r < 8; ++r)
    sf[(n0 + r) * 2048 + hcb + tid] = a[r];
}

// ---------------- naive a_src/a_dst dots (block per (n,h)) --------------------------
__global__ __launch_bounds__(64) void k_ad(const float* sf, const float* vecf, int l,
                                           float* asf, float* adf) {
  int b = blockIdx.x;            // n*4+h
  int n = b >> 2, h = b & 3;
  int lane = threadIdx.x;
  const float* s = sf + n * 2048 + h * 512;
  const float* as_ = vecf + 3728 + l * 2048 + h * 512;
  const float* ad_ = vecf + 9872 + l * 2048 + h * 512;
  float sa = 0.f, sd = 0.f;
  for (int c = lane; c < 512; c += 64) { sa = fmaf(s[c], as_[c], sa); sd = fmaf(s[c], ad_[c], sd); }
#pragma unroll
  for (int m = 1; m < 64; m <<= 1) { sa += __shfl_xor(sa, m, 64); sd += __shfl_xor(sd, m, 64); }
  if (lane == 0) { asf[b] = sa; adf[b] = sd; }
}

// ---------------- GAT attention softmax -> alpha bf16 hi/lo [dst][h*256+src] --------
__global__ __launch_bounds__(256) void k_alpha(const float* asf, const float* adf,
    const float* maskv, u16* a_hib, u16* a_lob) {
  int dd = blockIdx.x, s = threadIdx.x;
  int lane = s & 63, w = s >> 6;
  __shared__ float wr[2][4][4];
  float mk = maskv[dd * 256 + s];
  float lg[4];
#pragma unroll
  for (int h = 0; h < 4; ++h) {
    float v = adf[dd * 4 + h] + asf[s * 4 + h];
    lg[h] = lrelu(v) + mk;
  }
#pragma unroll
  for (int h = 0; h < 4; ++h) {
    float v = lg[h];
#pragma unroll
    for (int m = 1; m < 64; m <<= 1) v = fmaxf(v, __shfl_xor(v, m, 64));
    if (lane == 0) wr[0][h][w] = v;
  }
  __syncthreads();
  float e[4];
#pragma unroll
  for (int h = 0; h < 4; ++h) {
    float mx = fmaxf(fmaxf(wr[0][h][0], wr[0][h][1]), fmaxf(wr[0][h][2], wr[0][h][3]));
    float v = __expf(lg[h] - mx);
    e[h] = v;
#pragma unroll
    for (int m = 1; m < 64; m <<= 1) v += __shfl_xor(v, m, 64);
    if (lane == 0) wr[1][h][w] = v;
  }
  __syncthreads();
#pragma unroll
  for (int h = 0; h < 4; ++h) {
    float sm = wr[1][h][0] + wr[1][h][1] + wr[1][h][2] + wr[1][h][3];
    float v = e[h] / sm;
    u16 hi = f2bf(v);
    int o = dd * 1024 + h * 256 + s;
    a_hib[o] = hi;
    a_lob[o] = f2bf(v - bf2f(hi));    // v-hi exact in f32
  }
}

// ---------------- s transpose -> sT bf16 hi/lo: sT[c][h*256+n] = s[n][h*512+c] ------
__global__ __launch_bounds__(256) void k_st(const float* sf, u16* sT_hi, u16* sT_lo) {
  __shared__ float T[64][65];
  int tid = threadIdx.x;
  int hc0 = blockIdx.x * 64;
  int n0 = blockIdx.y * 64;
  int h = hc0 >> 9, c0 = hc0 & 511, q0 = h * 256 + n0;
  int cl = tid & 63, rw = tid >> 6;
#pragma unroll
  for (int rr = 0; rr < 16; ++rr) {
    int r = rr * 4 + rw;
    T[r][cl] = sf[(n0 + r) * 2048 + hc0 + cl];
  }
  __syncthreads();
#pragma unroll
  for (int rr = 0; rr < 16; ++rr) {
    int r = rr * 4 + rw;              // c-offset within tile
    float v = T[cl][r];               // stride-65 read: conflict-free
    u16 hi = f2bf(v);
    int o = (c0 + r) * 1024 + q0 + cl;
    sT_hi[o] = hi;
    sT_lo[o] = f2bf(v - bf2f(hi));
  }
}

// ---------------- aggregation as MFMA GEMM: x[i][c] = lrelu(0.25*A.B + b) -----------
__global__ __launch_bounds__(256) void k_aggm(const u16* a_hi, const u16* a_lo,
    const u16* sT_hi, const u16* sT_lo, const float* vecf, int l, float* xout) {
  int tid = threadIdx.x, lane = tid & 63, w = tid >> 6;
  int c0 = blockIdx.x * 32 + (w & 1) * 16;     // grid.x = 16
  int i0 = blockIdx.y * 32 + (w >> 1) * 16;    // grid.y = 8
  int kb = (lane >> 4) * 8;
  int ar = (i0 + (lane & 15)) * 1024 + kb;
  int br = (c0 + (lane & 15)) * 1024 + kb;
  f32x4 acc = (f32x4){0.f, 0.f, 0.f, 0.f};
#pragma unroll 4
  for (int k0 = 0; k0 < 1024; k0 += 32) {
    short8 ah = *(const short8*)(a_hi + ar + k0);
    short8 al = *(const short8*)(a_lo + ar + k0);
    short8 bh = *(const short8*)(sT_hi + br + k0);
    short8 bl = *(const short8*)(sT_lo + br + k0);
    acc = __builtin_amdgcn_mfma_f32_16x16x32_bf16(ah, bh, acc, 0, 0, 0);
    acc = __builtin_amdgcn_mfma_f32_16x16x32_bf16(ah, bl, acc, 0, 0, 0);
    acc = __builtin_amdgcn_mfma_f32_16x16x32_bf16(al, bh, acc, 0, 0, 0);
  }
  int c = c0 + (lane & 15);
  float b = vecf[16016 + l * 512 + c];
#pragma unroll
  for (int r = 0; r < 4; ++r) {
    int i = i0 + (lane >> 4) * 4 + r;
    xout[i * 512 + c] = lrelu(fmaf(acc[r], 0.25f, b));
  }
}

// ---------------- linear: out[i][c] = x[i].W[:,c] + bias; LDS-staged, 4 rows --------
// grid (2, 64), 256 thr. Same fmaf expression & k-order -> bit-identical.
__global__ __launch_bounds__(256) void k_op(const float* x, const float* Wf,
    const float* bias, float* out) {
  __shared__ float wS[16384];   // 64 KB
  __shared__ float eS[2048];    // 8 KB: 4 rows x 512
  int tid = threadIdx.x;
  int c = blockIdx.x * 256 + tid;            // grid.x = 2
  int i0 = blockIdx.y * 4;                   // grid.y = 64
  const float* xr = x + i0 * 512;
  for (int q = tid; q < 512; q += 256)
    *(float4*)(eS + q * 4) = *(const float4*)(xr + q * 4);
  float a0 = 0.f, a1 = 0.f, a2 = 0.f, a3 = 0.f;
  for (int kt = 0; kt < 8; ++kt) {
    __syncthreads();
    for (int q = tid; q < 4096; q += 256) {
      int row = q >> 6, c4 = q & 63;
      *(float4*)(wS + row * 256 + c4 * 4) =
          *(const float4*)(Wf + (kt * 64 + row) * 512 + blockIdx.x * 256 + c4 * 4);
    }
    __syncthreads();
    for (int kk = 0; kk < 64; kk += 2) {
      int k = kt * 64 + kk;
      float w0 = wS[kk * 256 + tid];
      float w1 = wS[(kk + 1) * 256 + tid];
      float2 x0 = *(const float2*)(eS + k);
      float2 x1 = *(const float2*)(eS + 512 + k);
      float2 x2 = *(const float2*)(eS + 1024 + k);
      float2 x3 = *(const float2*)(eS + 1536 + k);
      a0 = fmaf(x0.x, w0, fmaf(x0.y, w1, a0));
      a1 = fmaf(x1.x, w0, fmaf(x1.y, w1, a1));
      a2 = fmaf(x2.x, w0, fmaf(x2.y, w1, a2));
      a3 = fmaf(x3.x, w0, fmaf(x3.y, w1, a3));
    }
  }
  out[(i0 + 0) * 512 + c] = a0 + bias[c];
  out[(i0 + 1) * 512 + c] = a1 + bias[c];
  out[(i0 + 2) * 512 + c] = a2 + bias[c];
  out[(i0 + 3) * 512 + c] = a3 + bias[c];
}

// ---------------- output-proj LayerNorm + leaky -> f32 ------------------------------
__global__ __launch_bounds__(256) void k_ln(const float* t1, const float* vecf, float* h1f) {
  const float* g_ = vecf + 18064;
  const float* be_ = vecf + 18576;
  int row = blockIdx.x, tid = threadIdx.x, lane = tid & 63, w = tid >> 6;
  __shared__ float wr[2][4];
  float v0 = t1[row * 512 + tid];
  float v1 = t1[row * 512 + 256 + tid];
  float s = v0 + v1, s2 = fmaf(v0, v0, v1 * v1);
#pragma unroll
  for (int m = 1; m < 64; m <<= 1) { s += __shfl_xor(s, m, 64); s2 += __shfl_xor(s2, m, 64); }
  if (lane == 0) { wr[0][w] = s; wr[1][w] = s2; }
  __syncthreads();
  s = wr[0][0] + wr[0][1] + wr[0][2] + wr[0][3];
  s2 = wr[1][0] + wr[1][1] + wr[1][2] + wr[1][3];
  float m = s * (1.f / 512.f);
  float var = fmaxf(s2 * (1.f / 512.f) - m * m, 0.f);
  float iv = 1.f / sqrtf(var + 1e-5f);
  float z0 = (v0 - m) * iv * g_[tid] + be_[tid];
  float z1 = (v1 - m) * iv * g_[tid + 256] + be_[tid + 256];
  h1f[row * 512 + tid] = lrelu(z0);
  h1f[row * 512 + 256 + tid] = lrelu(z1);
}

// ---------------- final linear -> f32 out; LDS-staged, 4 rows -----------------------
__global__ __launch_bounds__(256) void k_op2(const float* x, const float* Wf,
    const float* vecf, float* outf) {
  __shared__ float wS[16384];   // 64 KB
  __shared__ float eS[2048];    // 8 KB
  int tid = threadIdx.x;
  int c = blockIdx.x * 256 + tid;            // grid.x = 2
  int i0 = blockIdx.y * 4;                   // grid.y = 64
  const float* xr = x + i0 * 512;
  for (int q = tid; q < 512; q += 256)
    *(float4*)(eS + q * 4) = *(const float4*)(xr + q * 4);
  float a0 = 0.f, a1 = 0.f, a2 = 0.f, a3 = 0.f;
  for (int kt = 0; kt < 8; ++kt) {
    __syncthreads();
    for (int q = tid; q < 4096; q += 256) {
      int row = q >> 6, c4 = q & 63;
      *(float4*)(wS + row * 256 + c4 * 4) =
          *(const float4*)(Wf + (kt * 64 + row) * 512 + blockIdx.x * 256 + c4 * 4);
    }
    __syncthreads();
    for (int kk = 0; kk < 64; kk += 2) {
      int k = kt * 64 + kk;
      float w0 = wS[kk * 256 + tid];
      float w1 = wS[(kk + 1) * 256 + tid];
      float2 x0 = *(const float2*)(eS + k);
      float2 x1 = *(const float2*)(eS + 512 + k);
      float2 x2 = *(const float2*)(eS + 1024 + k);
      float2 x3 = *(const float2*)(eS + 1536 + k);
      a0 = fmaf(x0.x, w0, fmaf(x0.y, w1, a0));
      a1 = fmaf(x1.x, w0, fmaf(x1.y, w1, a1));
      a2 = fmaf(x2.x, w0, fmaf(x2.y, w1, a2));
      a3 = fmaf(x3.x, w0, fmaf(x3.y, w1, a3));
    }
  }
  float b = vecf[19088 + c];
  outf[(i0 + 0) * 512 + c] = a0 + b;
  outf[(i0 + 1) * 512 + c] = a1 + b;
  outf[(i0 + 2) * 512 + c] = a2 + b;
  outf[(i0 + 3) * 512 + c] = a3 + b;
}

extern "C" void kernel_launch(void* const* d_in, const int* in_sizes, int n_in,
                              void* d_out, int out_size, void* d_ws, size_t ws_size,
                              hipStream_t stream) {
  (void)out_size;
  static const int dictT[23] = {0,1,2,3,4,5,6,7,8,9,10,11,12,13,14,15,16,17,18,19,20,21,22};
  static const int alphaT[23] = {6,11,7,10,9,12,8,4,0,3,2,5,1,13,15,14,16,21,17,20,19,22,18};
  const int* tbl = (n_in == 23 && in_sizes[0] == 512) ? alphaT : dictT;
  auto IN = [&](int role) -> const void* { return d_in[tbl[role]]; };

  float* out_f = (float*)d_out;                    // [256,512] f32
  float* act_f = out_f + 256 * 512;                // [256,256] f32 0/1
  float* ef_f  = out_f + 256 * 512 + 256 * 256;    // [256,256,128] f32

  char* cur = (char*)d_ws;
  auto alloc = [&](size_t bytes) -> void* {
    void* r = (void*)cur;
    cur += (bytes + 255) & ~(size_t)255;
    return r;
  };
  float* vecf    = (float*)alloc(20480 * 4);
  float* embf    = (float*)alloc(131072 * 4);
  float* epw1f   = (float*)alloc(524288 * 4);
  float* efw1f   = (float*)alloc(524288 * 4);
  float* gatWf   = (float*)alloc(3145728 * 4);
  float* opw1f   = (float*)alloc(262144 * 4);
  float* opw2f   = (float*)alloc(262144 * 4);
  float* efw2f   = (float*)alloc(65536 * 4);
  float* uvf     = (float*)alloc(524288 * 4);
  float* sf      = (float*)alloc(524288 * 4);
  float* asf     = (float*)alloc(1024 * 4);
  float* adf     = (float*)alloc(1024 * 4);
  float* xf      = (float*)alloc(262144 * 4);
  float* t1      = (float*)alloc(131072 * 4);
  float* h1f     = (float*)alloc(131072 * 4);
  float* maskv   = (float*)alloc(65536 * 4);
  double* sums   = (double*)alloc(1024 * 8);
  double* sumsq  = (double*)alloc(1024 * 8);
  double* crossep = (double*)alloc(65536 * 8);
  double* crossef = (double*)alloc(65536 * 8);
  u16* w2tb      = (u16*)alloc(65536 * 2);
  float* vfrag   = (float*)alloc(131072 * 4);
  int* flag      = (int*)alloc(256);
  if ((size_t)(cur - (char*)d_ws) > ws_size) return;

  // GAT-phase buffers aliased onto epw1f/efw1f (both dead after k_uv):
  u16* sT_hi = (u16*)epw1f;            // 512*1024 u16 = 1 MB
  u16* sT_lo = sT_hi + 524288;         // second 1 MB of epw1f's 2 MB
  u16* a_hib = (u16*)efw1f;            // 256*1024 u16 = 512 KB
  u16* a_lob = a_hib + 262144;         // next 512 KB of efw1f's 2 MB

  hipMemsetAsync(flag, 0, 256, stream);
  hipLaunchKernelGGL(k_detect, dim3(64), dim3(256), 0, stream, (const u16*)IN(0), flag);

  { // small vectors -> canonical f32
    VArgs va;
    auto setV = [&](int qi, int role, int dst, int n) { va.v[qi] = {IN(role), dst, n}; };
    setV(0, 2, 0, 512);       // ep_b1
    setV(1, 3, 512, 512);     // ep_g
    setV(2, 4, 1024, 512);    // ep_beta
    setV(3, 5, 1536, 512);    // ep_w2
    setV(4, 6, 2048, 1);      // ep_b2
    setV(5, 8, 2064, 512);    // ef_b1
    setV(6, 9, 2576, 512);    // ef_g
    setV(7, 10, 3088, 512);   // ef_beta
    setV(8, 12, 3600, 128);   // ef_b2
    setV(9, 14, 3728, 6144);  // gat_a_src
    setV(10, 15, 9872, 6144); // gat_a_dst
    setV(11, 16, 16016, 1536);// gat_b
    setV(12, 18, 17552, 512); // op_b1
    setV(13, 19, 18064, 512); // op_g
    setV(14, 20, 18576, 512); // op_beta
    setV(15, 22, 19088, 512); // op_b2
    hipLaunchKernelGGL(k_vec, dim3(16), dim3(256), 0, stream, va, (const int*)flag, vecf);
  }

  { // big matrices -> canonical f32
    CArgs ca;
    ca.src[0] = IN(0);  ca.dst[0] = embf;  ca.n[0] = 131072;
    ca.src[1] = IN(1);  ca.dst[1] = epw1f; ca.n[1] = 524288;
    ca.src[2] = IN(7);  ca.dst[2] = efw1f; ca.n[2] = 524288;
    ca.src[3] = IN(13); ca.dst[3] = gatWf; ca.n[3] = 3145728;
    ca.src[4] = IN(17); ca.dst[4] = opw1f; ca.n[4] = 262144;
    ca.src[5] = IN(21); ca.dst[5] = opw2f; ca.n[5] = 262144;
    ca.src[6] = IN(11); ca.dst[6] = efw2f; ca.n[6] = 65536;
    hipLaunchKernelGGL(k_cvt, dim3(2048, 7), dim3(256), 0, stream, ca, (const int*)flag);
  }
  hipLaunchKernelGGL(k_w2tb, dim3(256), dim3(256), 0, stream, efw2f, w2tb);

  hipLaunchKernelGGL(k_uv, dim3(2, 64, 4), dim3(256), 0, stream, embf, epw1f, efw1f, vecf, uvf);
  hipLaunchKernelGGL(k_vfr, dim3(512), dim3(256), 0, stream, uvf, vfrag);
  hipLaunchKernelGGL(k_stats64, dim3(1024), dim3(64), 0, stream, uvf, sums, sumsq);
  hipLaunchKernelGGL(k_cross, dim3(16, 16, 2), dim3(256), 0, stream, uvf, crossep, crossef);

  hipLaunchKernelGGL(k_ep_t, dim3(16, 16), dim3(256), 0, stream,
                     uvf, sums, sumsq, crossep, vecf, act_f, maskv);
  hipLaunchKernelGGL(k_ef, dim3(256), dim3(512), 0, stream,
                     uvf, sums, sumsq, crossef, vecf, w2tb, vfrag, ef_f);

  const float* xsrc = embf;
  for (int l = 0; l < 3; ++l) {
    hipLaunchKernelGGL(k_s, dim3(8, 32), dim3(256), 0, stream,
                       xsrc, gatWf + l * 1048576, sf);
    hipLaunchKernelGGL(k_ad, dim3(1024), dim3(64), 0, stream, sf, vecf, l, asf, adf);
    hipLaunchKernelGGL(k_alpha, dim3(256), dim3(256), 0, stream, asf, adf, maskv,
                       a_hib, a_lob);
    hipLaunchKernelGGL(k_st, dim3(32, 4), dim3(256), 0, stream, sf, sT_hi, sT_lo);
    float* xdst = xf + (l & 1) * 131072;
    hipLaunchKernelGGL(k_aggm, dim3(16, 8), dim3(256), 0, stream,
                       a_hib, a_lob, sT_hi, sT_lo, vecf, l, xdst);
    xsrc = xdst;
  }

  hipLaunchKernelGGL(k_op, dim3(2, 64), dim3(256), 0, stream, xsrc, opw1f, vecf + 17552, t1);
  hipLaunchKernelGGL(k_ln, dim3(256), dim3(256), 0, stream, t1, vecf, h1f);
  hipLaunchKernelGGL(k_op2, dim3(2, 64), dim3(256), 0, stream, h1f, opw2f, vecf, out_f);
}

// Round 10
// 409.949 us; speedup vs baseline: 1.4938x; 1.4938x over previous
//
#include <hip/hip_runtime.h>

// NeuralAudioGraph: N=256, D=H=512, E=128, 4 heads, 3 GAT layers.
// r17: revert r16's LDS-staging regressions (k_uv/k_op/k_op2 back to r15
// streaming: 64-lane x 4B loads = 4 full cache lines/instr = cheap; r16's
// 80KB-LDS k_s dropped to 1 block/CU, Occ 10%, 62.6us) and instead convert
// k_s to MFMA with the k_aggm-VALIDATED bf16 hi/lo 3-product (AhBh+AhBl+AlBh,
// f32 acc): per layer k_wfr re-packs W[512][2048] into fragment-linear
// interleaved hi/lo (4MB), k_xb packs x (512KB), k_sm = 512-block GEMM with
// fully-line-utilized loads. Cost model from r8-r16: time ~ distinct cache
// lines requested per SIMD (~13cyc/line); keep >=2 blocks/CU.
// Baseline r15: 458us, absmax 0.0078125.

typedef __attribute__((ext_vector_type(8))) short short8;   // 8 x bf16 (MFMA frag)
typedef __attribute__((ext_vector_type(4))) float f32x4;    // MFMA accumulator
typedef unsigned short u16;
typedef unsigned int u32;

__device__ __forceinline__ float bf2f(u16 h) { return __uint_as_float(((u32)h) << 16); }
__device__ __forceinline__ u16 f2bf(float f) {
  u32 u = __float_as_uint(f);
  u += 0x7fffu + ((u >> 16) & 1u);   // round-to-nearest-even
  return (u16)(u >> 16);
}
__device__ __forceinline__ float lrelu(float v) { return fmaxf(v, 0.2f * v); }
__device__ __forceinline__ float ldany(int f32mode, const void* p, int i) {
  return f32mode ? ((const float*)p)[i] : bf2f(((const u16*)p)[i]);
}

// ---------------- dtype detector ----------------------------------------------------
__global__ __launch_bounds__(256) void k_detect(const u16* emb, int* flag) {
  bool big = false;
  for (int i = blockIdx.x * 256 + threadIdx.x; i < 131072; i += 256 * 64) {
    float v = bf2f(emb[i]);
    big |= !(fabsf(v) <= 1e6f);
  }
  unsigned long long m = __ballot(big);
  if (m && (threadIdx.x & 63) == 0) atomicOr(flag, 1);
}

// ---------------- small-vector ingest -> canonical f32 ------------------------------
struct VD { const void* src; int dst, n; };
struct VArgs { VD v[16]; };
__global__ __launch_bounds__(256) void k_vec(VArgs a, const int* flag, float* out) {
  int f = *flag;
  VD d = a.v[blockIdx.x];
  for (int i = threadIdx.x; i < d.n; i += 256)
    out[d.dst + i] = ldany(f, d.src, i);
}

// ---------------- big-matrix ingest -> canonical f32 --------------------------------
struct CArgs { const void* src[7]; float* dst[7]; int n[7]; };
__global__ __launch_bounds__(256) void k_cvt(CArgs a, const int* flag) {
  int f = *flag;
  int e = blockIdx.y;
  const void* s = a.src[e];
  float* d = a.dst[e];
  int n = a.n[e];
  for (int i = blockIdx.x * 256 + threadIdx.x; i < n; i += 2048 * 256)
    d[i] = ldany(f, s, i);
}

// ---------------- ef_w2 f32 [512][128] -> bf16 MFMA-fragment-linear -----------------
// w2fr[(kc*8+nt)*512 + l*8 + e] = bf16(w2[c = kc*32+(l>>4)*8+e][n = nt*16+(l&15)])
__global__ __launch_bounds__(256) void k_w2tb(const float* efw2f, u16* w2fr) {
  int idx = blockIdx.x * 256 + threadIdx.x;   // 65536
  int e = idx & 7, l = (idx >> 3) & 63, nt = (idx >> 9) & 7, kc = idx >> 12;
  int n = nt * 16 + (l & 15);
  int c = kc * 32 + ((l >> 4) << 3) + e;
  w2fr[idx] = f2bf(efw2f[c * 128 + n]);
}

// ---------------- V rows -> f32 MFMA-fragment-linear --------------------------------
// vfrag[jb*8192 + kc*512 + l*8 + e] = V[jb*16+(l&15)][kc*32+(l>>4)*8+e]
__global__ __launch_bounds__(256) void k_vfr(const float* uvf, float* vfrag) {
  const float* V = uvf + 393216;
  int idx = blockIdx.x * 256 + threadIdx.x;   // grid 512 -> 131072
  int e = idx & 7, l = (idx >> 3) & 63, kc = (idx >> 9) & 15, jb = idx >> 13;
  int j = jb * 16 + (l & 15);
  int c = kc * 32 + ((l >> 4) << 3) + e;
  vfrag[idx] = V[j * 512 + c];
}

// ---------------- GAT W[l] -> fragment-linear interleaved bf16 hi/lo ----------------
// wfr[((nt*16+kc)*64+lane)*16 + {0..7:hi, 8..15:lo}] with value
// W[kc*32+(lane>>4)*8+e][nt*16+(lane&15)], nt in [0,128), kc in [0,16).
__global__ __launch_bounds__(256) void k_wfr(const float* Wf, u16* wfr) {
  int idx = blockIdx.x * 256 + threadIdx.x;   // 131072
  int lane = idx & 63, kc = (idx >> 6) & 15, nt = idx >> 10;
  int n = nt * 16 + (lane & 15);
  int c0 = kc * 32 + ((lane >> 4) << 3);
  u16* dst = wfr + idx * 16;
#pragma unroll
  for (int e = 0; e < 8; ++e) {
    float v = Wf[(c0 + e) * 2048 + n];
    u16 hi = f2bf(v);
    dst[e] = hi;
    dst[8 + e] = f2bf(v - bf2f(hi));
  }
}

// ---------------- x -> fragment-linear interleaved bf16 hi/lo -----------------------
// xfr[((it*16+kc)*64+lane)*16 + {hi8,lo8}] = x[it*16+(lane&15)][kc*32+(lane>>4)*8+e]
__global__ __launch_bounds__(256) void k_xb(const float* x, u16* xfr) {
  int idx = blockIdx.x * 256 + threadIdx.x;   // 16384
  int lane = idx & 63, kc = (idx >> 6) & 15, it = idx >> 10;
  int i = it * 16 + (lane & 15);
  int c0 = kc * 32 + ((lane >> 4) << 3);
  const float* src = x + i * 512 + c0;
  float4 v0 = *(const float4*)(src);
  float4 v1 = *(const float4*)(src + 4);
  float vv[8] = {v0.x, v0.y, v0.z, v0.w, v1.x, v1.y, v1.z, v1.w};
  u16* dst = xfr + idx * 16;
#pragma unroll
  for (int e = 0; e < 8; ++e) {
    u16 hi = f2bf(vv[e]);
    dst[e] = hi;
    dst[8 + e] = f2bf(vv[e] - bf2f(hi));
  }
}

// ---------------- GAT s = x @ W[l] as MFMA (hi/lo 3-product, k_aggm-style) ----------
// grid (64, 8), 256 thr = 4 waves; wave w owns 16x16 tile at rows i0+(w>>1)*16,
// cols n0+(w&1)*16. All fragment loads contiguous 16B/lane from frag-linear bufs.
__global__ __launch_bounds__(256) void k_sm(const u16* xfr, const u16* wfr, float* sf) {
  int tid = threadIdx.x, lane = tid & 63, w = tid >> 6;
  int n0 = blockIdx.x * 32 + (w & 1) * 16;     // grid.x = 64
  int i0 = blockIdx.y * 32 + (w >> 1) * 16;    // grid.y = 8
  int it = i0 >> 4, nt = n0 >> 4;
  const u16* ap = xfr + (it * 16) * 1024 + lane * 16;
  const u16* bp = wfr + (nt * 16) * 1024 + lane * 16;
  f32x4 acc = (f32x4){0.f, 0.f, 0.f, 0.f};
#pragma unroll
  for (int kc = 0; kc < 16; ++kc) {
    short8 ah = *(const short8*)(ap + kc * 1024);
    short8 al = *(const short8*)(ap + kc * 1024 + 8);
    short8 bh = *(const short8*)(bp + kc * 1024);
    short8 bl = *(const short8*)(bp + kc * 1024 + 8);
    acc = __builtin_amdgcn_mfma_f32_16x16x32_bf16(ah, bh, acc, 0, 0, 0);
    acc = __builtin_amdgcn_mfma_f32_16x16x32_bf16(ah, bl, acc, 0, 0, 0);
    acc = __builtin_amdgcn_mfma_f32_16x16x32_bf16(al, bh, acc, 0, 0, 0);
  }
  int col = n0 + (lane & 15);
#pragma unroll
  for (int r = 0; r < 4; ++r) {
    int row = i0 + (lane >> 4) * 4 + r;
    sf[row * 2048 + col] = acc[r];
  }
}

// ---------------- U/V = emb @ W1 halves; f64 for ep (arr 0,1), f32 for ef -----------
// grid (2, 64, 4): x = col half, y = 4-row group, z = arr. (r15 streaming version)
__global__ __launch_bounds__(256) void k_uv(const float* embf, const float* epw1f,
    const float* efw1f, const float* vecf, float* uvf) {
  int tid = threadIdx.x;
  int col = blockIdx.x * 256 + tid;
  int r0 = blockIdx.y * 4;
  int arr = blockIdx.z;
  const float* W = ((arr < 2) ? epw1f : efw1f) + (arr & 1) * 262144 + col;
  const float* e = embf + r0 * 512;
  float bias = (arr == 1) ? vecf[col] : (arr == 3) ? vecf[2064 + col] : 0.f;
  float* outp = uvf + arr * 131072 + r0 * 512 + col;
  if (arr < 2) {
    double a0 = 0.0, a1 = 0.0, a2 = 0.0, a3 = 0.0;
    for (int k = 0; k < 512; k += 2) {
      double w0 = (double)W[k * 512];
      double w1 = (double)W[(k + 1) * 512];
      float2 e0 = *(const float2*)(e + k);
      float2 e1 = *(const float2*)(e + 512 + k);
      float2 e2 = *(const float2*)(e + 1024 + k);
      float2 e3 = *(const float2*)(e + 1536 + k);
      a0 += (double)e0.x * w0 + (double)e0.y * w1;
      a1 += (double)e1.x * w0 + (double)e1.y * w1;
      a2 += (double)e2.x * w0 + (double)e2.y * w1;
      a3 += (double)e3.x * w0 + (double)e3.y * w1;
    }
    outp[0]    = (float)(a0 + (double)bias);
    outp[512]  = (float)(a1 + (double)bias);
    outp[1024] = (float)(a2 + (double)bias);
    outp[1536] = (float)(a3 + (double)bias);
  } else {
    float a0 = 0.f, a1 = 0.f, a2 = 0.f, a3 = 0.f;
    for (int k = 0; k < 512; k += 2) {
      float w0 = W[k * 512], w1 = W[(k + 1) * 512];
      float2 e0 = *(const float2*)(e + k);
      float2 e1 = *(const float2*)(e + 512 + k);
      float2 e2 = *(const float2*)(e + 1024 + k);
      float2 e3 = *(const float2*)(e + 1536 + k);
      a0 = fmaf(e0.x, w0, fmaf(e0.y, w1, a0));
      a1 = fmaf(e1.x, w0, fmaf(e1.y, w1, a1));
      a2 = fmaf(e2.x, w0, fmaf(e2.y, w1, a2));
      a3 = fmaf(e3.x, w0, fmaf(e3.y, w1, a3));
    }
    outp[0]    = a0 + bias;
    outp[512]  = a1 + bias;
    outp[1024] = a2 + bias;
    outp[1536] = a3 + bias;
  }
}

// ---------------- f64 row sums / sums-of-squares ------------------------------------
__global__ __launch_bounds__(64) void k_stats64(const float* uvf, double* sums, double* sumsq) {
  int bid = blockIdx.x;           // arr*256 + row
  int lane = threadIdx.x;
  const float* p = uvf + bid * 512;
  double s = 0.0, s2 = 0.0;
  for (int q = lane; q < 512; q += 64) { double v = p[q]; s += v; s2 += v * v; }
#pragma unroll
  for (int m = 1; m < 64; m <<= 1) { s += __shfl_xor(s, m, 64); s2 += __shfl_xor(s2, m, 64); }
  if (lane == 0) { sums[bid] = s; sumsq[bid] = s2; }
}

// ---------------- cross[i][j] = U_i . V_j (f64): z=0 -> ep, z=1 -> ef ---------------
__global__ __launch_bounds__(256) void k_cross(const float* uvf, double* crossep,
                                               double* crossef) {
  __shared__ float Uc[16][132], Vc[16][132];
  int z = blockIdx.z;
  const float* U = uvf + z * 262144;
  const float* V = U + 131072;
  double* out = z ? crossef : crossep;
  int tid = threadIdx.x, ti = tid & 15, tj = tid >> 4;
  int i0 = blockIdx.y * 16, j0 = blockIdx.x * 16;
  double acc = 0.0;
  for (int c0 = 0; c0 < 512; c0 += 128) {
    __syncthreads();
    for (int idx = tid; idx < 2048; idx += 256) {
      int r = idx >> 7, c = idx & 127;
      Uc[r][c] = U[(i0 + r) * 512 + c0 + c];
      Vc[r][c] = V[(j0 + r) * 512 + c0 + c];
    }
    __syncthreads();
#pragma unroll
    for (int c4 = 0; c4 < 128; c4 += 4) {
      float4 uu = *(const float4*)&Uc[ti][c4];
      float4 vv = *(const float4*)&Vc[tj][c4];
      float p = fmaf(uu.x, vv.x, fmaf(uu.y, vv.y, fmaf(uu.z, vv.z, uu.w * vv.w)));
      acc += (double)p;
    }
  }
  out[(i0 + ti) * 256 + j0 + tj] = acc;
}

// ---------------- edge predictor, stats-based tiled (1 thread / pair) ---------------
__global__ __launch_bounds__(256) void k_ep_t(const float* uvf, const double* sums,
    const double* sumsq, const double* crossep, const float* vecf,
    float* act, float* maskv) {
  __shared__ float Uc[16][132], Vc[16][132];
  int tid = threadIdx.x, ti = tid & 15, tj = tid >> 4;
  int i0 = blockIdx.y * 16, j0 = blockIdx.x * 16;
  int i = i0 + ti, j = j0 + tj;
  double md = (sums[i] + sums[256 + j]) * (1.0 / 512.0);
  double qd = (sumsq[i] + 2.0 * crossep[i * 256 + j] + sumsq[256 + j]) * (1.0 / 512.0);
  float iv = (float)(1.0 / sqrt(qd - md * md + 1e-5));
  float bb = (float)(-md) * iv;
  const float* U = uvf;
  const float* V = uvf + 131072;
  const float* g_ = vecf + 512;
  const float* be_ = vecf + 1024;
  const float* w2_ = vecf + 1536;
  double acc = 0.0;
  for (int c0 = 0; c0 < 512; c0 += 128) {
    __syncthreads();
    for (int idx = tid; idx < 2048; idx += 256) {
      int r = idx >> 7, c = idx & 127;
      Uc[r][c] = U[(i0 + r) * 512 + c0 + c];
      Vc[r][c] = V[(j0 + r) * 512 + c0 + c];
    }
    __syncthreads();
#pragma unroll
    for (int c4 = 0; c4 < 128; c4 += 4) {
      float4 uu = *(const float4*)&Uc[ti][c4];
      float4 vv = *(const float4*)&Vc[tj][c4];
      float4 gg = *(const float4*)(g_ + c0 + c4);
      float4 b4 = *(const float4*)(be_ + c0 + c4);
      float4 w4 = *(const float4*)(w2_ + c0 + c4);
      float z, s4 = 0.f;
      z = fmaf(fmaf(uu.x + vv.x, iv, bb), gg.x, b4.x); s4 = fmaf(lrelu(z), w4.x, s4);
      z = fmaf(fmaf(uu.y + vv.y, iv, bb), gg.y, b4.y); s4 = fmaf(lrelu(z), w4.y, s4);
      z = fmaf(fmaf(uu.z + vv.z, iv, bb), gg.z, b4.z); s4 = fmaf(lrelu(z), w4.z, s4);
      z = fmaf(fmaf(uu.w + vv.w, iv, bb), gg.w, b4.w); s4 = fmaf(lrelu(z), w4.w, s4);
      acc += (double)s4;
    }
  }
  double logit = acc + (double)vecf[2048];
  bool a = (logit > 0.0) && (i != j);
  act[i * 256 + j] = a ? 1.0f : 0.0f;
  maskv[j * 256 + i] = (a || i == j) ? 0.f : -1e9f;         // adj[dst][src] mask
}

// ---------------- edge features: all-LDS inner loop + bf16 MFMA (r15, validated) ----
__global__ __launch_bounds__(512, 2) void k_ef(const float* uvf, const double* sums,
    const double* sumsq, const double* crossef, const float* vecf,
    const u16* w2fr, const float* vfrag, float* ef_f) {
  __shared__ u16 w2S[16384];                 // 32 KB: 4 kc x 8 nt x 512
  __shared__ float vS0[4096], vS1[4096];     // 16+16 KB
  __shared__ float uS[8192];                 // 32 KB: 16 rows x 512
  __shared__ float gS[512], beS[512];        // 4 KB
  int tid = threadIdx.x;
  int lane = tid & 63, w = tid >> 6;         // w 0..7
  int bx = blockIdx.x;
  int bi = bx >> 4, bj = bx & 15;
  int i0 = bi * 16;
  int iA = i0 + w * 2, iB = iA + 1;
  int l15 = lane & 15;
  int j = bj * 16 + l15;
  int ksl = (lane >> 4) * 8;

  double sj = sums[768 + j], s2j = sumsq[768 + j];
  double mA = (sums[512 + iA] + sj) * (1.0 / 512.0);
  double qA = (sumsq[512 + iA] + 2.0 * crossef[iA * 256 + j] + s2j) * (1.0 / 512.0);
  float ivA = (float)(1.0 / sqrt(qA - mA * mA + 1e-5));
  float bbA = (float)(-mA) * ivA;
  double mB = (sums[512 + iB] + sj) * (1.0 / 512.0);
  double qB = (sumsq[512 + iB] + 2.0 * crossef[iB * 256 + j] + s2j) * (1.0 / 512.0);
  float ivB = (float)(1.0 / sqrt(qB - mB * mB + 1e-5));
  float bbB = (float)(-mB) * ivB;

  const float* Vg = vfrag + bj * 8192;
  for (int q = tid; q < 2048; q += 512) {
    float4 v = *(const float4*)(Vg + q * 4);
    int kc = q >> 7, r = q & 127, ln = r >> 1;
    if (r & 1) *(float4*)(vS1 + kc * 256 + ln * 4) = v;
    else       *(float4*)(vS0 + kc * 256 + ln * 4) = v;
  }
  const float* Ug = uvf + 262144 + i0 * 512;
  for (int q = tid; q < 2048; q += 512)
    *(float4*)(uS + q * 4) = *(const float4*)(Ug + q * 4);
  if (tid < 128)      *(float4*)(gS + tid * 4)  = *(const float4*)(vecf + 2576 + tid * 4);
  else if (tid < 256) *(float4*)(beS + (tid - 128) * 4) = *(const float4*)(vecf + 3088 + (tid - 128) * 4);

  f32x4 acc[2][8];
#pragma unroll
  for (int ai = 0; ai < 2; ++ai)
#pragma unroll
    for (int bq = 0; bq < 8; ++bq) acc[ai][bq] = (f32x4){0.f, 0.f, 0.f, 0.f};

  auto H8 = [&](float4 u0, float4 u1, float4 v0, float4 v1, float4 g0, float4 g1,
                float4 e0, float4 e1, float iv, float bb) -> short8 {
    short8 a; float z;
    z = fmaf(u0.x + v0.x, iv, bb); z = fmaf(z, g0.x, e0.x); a[0] = (short)f2bf(lrelu(z));
    z = fmaf(u0.y + v0.y, iv, bb); z = fmaf(z, g0.y, e0.y); a[1] = (short)f2bf(lrelu(z));
    z = fmaf(u0.z + v0.z, iv, bb); z = fmaf(z, g0.z, e0.z); a[2] = (short)f2bf(lrelu(z));
    z = fmaf(u0.w + v0.w, iv, bb); z = fmaf(z, g0.w, e0.w); a[3] = (short)f2bf(lrelu(z));
    z = fmaf(u1.x + v1.x, iv, bb); z = fmaf(z, g1.x, e1.x); a[4] = (short)f2bf(lrelu(z));
    z = fmaf(u1.y + v1.y, iv, bb); z = fmaf(z, g1.y, e1.y); a[5] = (short)f2bf(lrelu(z));
    z = fmaf(u1.z + v1.z, iv, bb); z = fmaf(z, g1.z, e1.z); a[6] = (short)f2bf(lrelu(z));
    z = fmaf(u1.w + v1.w, iv, bb); z = fmaf(z, g1.w, e1.w); a[7] = (short)f2bf(lrelu(z));
    return a;
  };

  const float* uA = uS + (w * 2) * 512;
  const float* uB = uA + 512;

  for (int kq = 0; kq < 4; ++kq) {
    __syncthreads();
    const short8* src = (const short8*)(w2fr + kq * 16384);
    for (int q = tid; q < 2048; q += 512)
      *(short8*)(w2S + q * 8) = src[q];
    __syncthreads();
#pragma unroll
    for (int kk = 0; kk < 4; ++kk) {
      int kc = kq * 4 + kk;
      int k0 = kc * 32 + ksl;
      float4 u0 = *(const float4*)(uA + k0);
      float4 u1 = *(const float4*)(uA + k0 + 4);
      float4 b0 = *(const float4*)(uB + k0);
      float4 b1 = *(const float4*)(uB + k0 + 4);
      float4 v0 = *(const float4*)(vS0 + kc * 256 + lane * 4);
      float4 v1 = *(const float4*)(vS1 + kc * 256 + lane * 4);
      float4 g0 = *(const float4*)(gS + k0);
      float4 g1 = *(const float4*)(gS + k0 + 4);
      float4 e0 = *(const float4*)(beS + k0);
      float4 e1 = *(const float4*)(beS + k0 + 4);
      short8 aA = H8(u0, u1, v0, v1, g0, g1, e0, e1, ivA, bbA);
      short8 aB = H8(b0, b1, v0, v1, g0, g1, e0, e1, ivB, bbB);
#pragma unroll
      for (int nt = 0; nt < 8; ++nt) {
        short8 bv = *(const short8*)(w2S + kk * 4096 + nt * 512 + lane * 8);
        acc[0][nt] = __builtin_amdgcn_mfma_f32_16x16x32_bf16(aA, bv, acc[0][nt], 0, 0, 0);
        acc[1][nt] = __builtin_amdgcn_mfma_f32_16x16x32_bf16(aB, bv, acc[1][nt], 0, 0, 0);
      }
    }
  }
#pragma unroll
  for (int mi = 0; mi < 2; ++mi) {
    int ii = mi ? iB : iA;
#pragma unroll
    for (int nt = 0; nt < 8; ++nt) {
      int n = nt * 16 + l15;
      float bias = vecf[3600 + n];
#pragma unroll
      for (int r = 0; r < 4; ++r) {
        int row = (lane >> 4) * 4 + r;
        ef_f[(ii * 256 + bj * 16 + row) * 128 + n] = acc[mi][nt][r] + bias;
      }
    }
  }
}

// ---------------- naive a_src/a_dst dots (block per (n,h)) --------------------------
__global__ __launch_bounds__(64) void k_ad(const float* sf, const float* vecf, int l,
                                           float* asf, float* adf) {
  int b = blockIdx.x;            // n*4+h
  int n = b >> 2, h = b & 3;
  int lane = threadIdx.x;
  const float* s = sf + n * 2048 + h * 512;
  const float* as_ = vecf + 3728 + l * 2048 + h * 512;
  const float* ad_ = vecf + 9872 + l * 2048 + h * 512;
  float sa = 0.f, sd = 0.f;
  for (int c = lane; c < 512; c += 64) { sa = fmaf(s[c], as_[c], sa); sd = fmaf(s[c], ad_[c], sd); }
#pragma unroll
  for (int m = 1; m < 64; m <<= 1) { sa += __shfl_xor(sa, m, 64); sd += __shfl_xor(sd, m, 64); }
  if (lane == 0) { asf[b] = sa; adf[b] = sd; }
}

// ---------------- GAT attention softmax -> alpha bf16 hi/lo [dst][h*256+src] --------
__global__ __launch_bounds__(256) void k_alpha(const float* asf, const float* adf,
    const float* maskv, u16* a_hib, u16* a_lob) {
  int dd = blockIdx.x, s = threadIdx.x;
  int lane = s & 63, w = s >> 6;
  __shared__ float wr[2][4][4];
  float mk = maskv[dd * 256 + s];
  float lg[4];
#pragma unroll
  for (int h = 0; h < 4; ++h) {
    float v = adf[dd * 4 + h] + asf[s * 4 + h];
    lg[h] = lrelu(v) + mk;
  }
#pragma unroll
  for (int h = 0; h < 4; ++h) {
    float v = lg[h];
#pragma unroll
    for (int m = 1; m < 64; m <<= 1) v = fmaxf(v, __shfl_xor(v, m, 64));
    if (lane == 0) wr[0][h][w] = v;
  }
  __syncthreads();
  float e[4];
#pragma unroll
  for (int h = 0; h < 4; ++h) {
    float mx = fmaxf(fmaxf(wr[0][h][0], wr[0][h][1]), fmaxf(wr[0][h][2], wr[0][h][3]));
    float v = __expf(lg[h] - mx);
    e[h] = v;
#pragma unroll
    for (int m = 1; m < 64; m <<= 1) v += __shfl_xor(v, m, 64);
    if (lane == 0) wr[1][h][w] = v;
  }
  __syncthreads();
#pragma unroll
  for (int h = 0; h < 4; ++h) {
    float sm = wr[1][h][0] + wr[1][h][1] + wr[1][h][2] + wr[1][h][3];
    float v = e[h] / sm;
    u16 hi = f2bf(v);
    int o = dd * 1024 + h * 256 + s;
    a_hib[o] = hi;
    a_lob[o] = f2bf(v - bf2f(hi));    // v-hi exact in f32
  }
}

// ---------------- s transpose -> sT bf16 hi/lo: sT[c][h*256+n] = s[n][h*512+c] ------
__global__ __launch_bounds__(256) void k_st(const float* sf, u16* sT_hi, u16* sT_lo) {
  __shared__ float T[64][65];
  int tid = threadIdx.x;
  int hc0 = blockIdx.x * 64;
  int n0 = blockIdx.y * 64;
  int h = hc0 >> 9, c0 = hc0 & 511, q0 = h * 256 + n0;
  int cl = tid & 63, rw = tid >> 6;
#pragma unroll
  for (int rr = 0; rr < 16; ++rr) {
    int r = rr * 4 + rw;
    T[r][cl] = sf[(n0 + r) * 2048 + hc0 + cl];
  }
  __syncthreads();
#pragma unroll
  for (int rr = 0; rr < 16; ++rr) {
    int r = rr * 4 + rw;              // c-offset within tile
    float v = T[cl][r];               // stride-65 read: conflict-free
    u16 hi = f2bf(v);
    int o = (c0 + r) * 1024 + q0 + cl;
    sT_hi[o] = hi;
    sT_lo[o] = f2bf(v - bf2f(hi));
  }
}

// ---------------- aggregation as MFMA GEMM: x[i][c] = lrelu(0.25*A.B + b) -----------
__global__ __launch_bounds__(256) void k_aggm(const u16* a_hi, const u16* a_lo,
    const u16* sT_hi, const u16* sT_lo, const float* vecf, int l, float* xout) {
  int tid = threadIdx.x, lane = tid & 63, w = tid >> 6;
  int c0 = blockIdx.x * 32 + (w & 1) * 16;     // grid.x = 16
  int i0 = blockIdx.y * 32 + (w >> 1) * 16;    // grid.y = 8
  int kb = (lane >> 4) * 8;
  int ar = (i0 + (lane & 15)) * 1024 + kb;
  int br = (c0 + (lane & 15)) * 1024 + kb;
  f32x4 acc = (f32x4){0.f, 0.f, 0.f, 0.f};
#pragma unroll 4
  for (int k0 = 0; k0 < 1024; k0 += 32) {
    short8 ah = *(const short8*)(a_hi + ar + k0);
    short8 al = *(const short8*)(a_lo + ar + k0);
    short8 bh = *(const short8*)(sT_hi + br + k0);
    short8 bl = *(const short8*)(sT_lo + br + k0);
    acc = __builtin_amdgcn_mfma_f32_16x16x32_bf16(ah, bh, acc, 0, 0, 0);
    acc = __builtin_amdgcn_mfma_f32_16x16x32_bf16(ah, bl, acc, 0, 0, 0);
    acc = __builtin_amdgcn_mfma_f32_16x16x32_bf16(al, bh, acc, 0, 0, 0);
  }
  int c = c0 + (lane & 15);
  float b = vecf[16016 + l * 512 + c];
#pragma unroll
  for (int r = 0; r < 4; ++r) {
    int i = i0 + (lane >> 4) * 4 + r;
    xout[i * 512 + c] = lrelu(fmaf(acc[r], 0.25f, b));
  }
}

// ---------------- linear: out[i][c] = x[i].W[:,c] + bias; 2 rows/thread -------------
__global__ __launch_bounds__(256) void k_op(const float* x, const float* Wf,
    const float* bias, float* out) {
  int tid = threadIdx.x;
  int c = blockIdx.x * 256 + tid;            // grid.x = 2
  int i0 = blockIdx.y * 2;                   // grid.y = 128
  const float* xr = x + i0 * 512;
  float a0 = 0.f, a1 = 0.f;
  for (int k = 0; k < 512; k += 2) {
    float w0 = Wf[k * 512 + c], w1 = Wf[(k + 1) * 512 + c];
    float2 x0 = *(const float2*)(xr + k);
    float2 x1 = *(const float2*)(xr + 512 + k);
    a0 = fmaf(x0.x, w0, fmaf(x0.y, w1, a0));
    a1 = fmaf(x1.x, w0, fmaf(x1.y, w1, a1));
  }
  out[(i0 + 0) * 512 + c] = a0 + bias[c];
  out[(i0 + 1) * 512 + c] = a1 + bias[c];
}

// ---------------- output-proj LayerNorm + leaky -> f32 ------------------------------
__global__ __launch_bounds__(256) void k_ln(const float* t1, const float* vecf, float* h1f) {
  const float* g_ = vecf + 18064;
  const float* be_ = vecf + 18576;
  int row = blockIdx.x, tid = threadIdx.x, lane = tid & 63, w = tid >> 6;
  __shared__ float wr[2][4];
  float v0 = t1[row * 512 + tid];
  float v1 = t1[row * 512 + 256 + tid];
  float s = v0 + v1, s2 = fmaf(v0, v0, v1 * v1);
#pragma unroll
  for (int m = 1; m < 64; m <<= 1) { s += __shfl_xor(s, m, 64); s2 += __shfl_xor(s2, m, 64); }
  if (lane == 0) { wr[0][w] = s; wr[1][w] = s2; }
  __syncthreads();
  s = wr[0][0] + wr[0][1] + wr[0][2] + wr[0][3];
  s2 = wr[1][0] + wr[1][1] + wr[1][2] + wr[1][3];
  float m = s * (1.f / 512.f);
  float var = fmaxf(s2 * (1.f / 512.f) - m * m, 0.f);
  float iv = 1.f / sqrtf(var + 1e-5f);
  float z0 = (v0 - m) * iv * g_[tid] + be_[tid];
  float z1 = (v1 - m) * iv * g_[tid + 256] + be_[tid + 256];
  h1f[row * 512 + tid] = lrelu(z0);
  h1f[row * 512 + 256 + tid] = lrelu(z1);
}

// ---------------- final linear -> f32 out; 2 rows/thread ----------------------------
__global__ __launch_bounds__(256) void k_op2(const float* x, const float* Wf,
    const float* vecf, float* outf) {
  int tid = threadIdx.x;
  int c = blockIdx.x * 256 + tid;            // grid.x = 2
  int i0 = blockIdx.y * 2;                   // grid.y = 128
  const float* xr = x + i0 * 512;
  float a0 = 0.f, a1 = 0.f;
  for (int k = 0; k < 512; k += 2) {
    float w0 = Wf[k * 512 + c], w1 = Wf[(k + 1) * 512 + c];
    float2 x0 = *(const float2*)(xr + k);
    float2 x1 = *(const float2*)(xr + 512 + k);
    a0 = fmaf(x0.x, w0, fmaf(x0.y, w1, a0));
    a1 = fmaf(x1.x, w0, fmaf(x1.y, w1, a1));
  }
  outf[(i0 + 0) * 512 + c] = a0 + vecf[19088 + c];
  outf[(i0 + 1) * 512 + c] = a1 + vecf[19088 + c];
}

extern "C" void kernel_launch(void* const* d_in, const int* in_sizes, int n_in,
                              void* d_out, int out_size, void* d_ws, size_t ws_size,
                              hipStream_t stream) {
  (void)out_size;
  static const int dictT[23] = {0,1,2,3,4,5,6,7,8,9,10,11,12,13,14,15,16,17,18,19,20,21,22};
  static const int alphaT[23] = {6,11,7,10,9,12,8,4,0,3,2,5,1,13,15,14,16,21,17,20,19,22,18};
  const int* tbl = (n_in == 23 && in_sizes[0] == 512) ? alphaT : dictT;
  auto IN = [&](int role) -> const void* { return d_in[tbl[role]]; };

  float* out_f = (float*)d_out;                    // [256,512] f32
  float* act_f = out_f + 256 * 512;                // [256,256] f32 0/1
  float* ef_f  = out_f + 256 * 512 + 256 * 256;    // [256,256,128] f32

  char* cur = (char*)d_ws;
  auto alloc = [&](size_t bytes) -> void* {
    void* r = (void*)cur;
    cur += (bytes + 255) & ~(size_t)255;
    return r;
  };
  float* vecf    = (float*)alloc(20480 * 4);
  float* embf    = (float*)alloc(131072 * 4);
  float* epw1f   = (float*)alloc(524288 * 4);
  float* efw1f   = (float*)alloc(524288 * 4);
  float* gatWf   = (float*)alloc(3145728 * 4);
  float* opw1f   = (float*)alloc(262144 * 4);
  float* opw2f   = (float*)alloc(262144 * 4);
  float* efw2f   = (float*)alloc(65536 * 4);
  float* uvf     = (float*)alloc(524288 * 4);
  float* sf      = (float*)alloc(524288 * 4);
  float* asf     = (float*)alloc(1024 * 4);
  float* adf     = (float*)alloc(1024 * 4);
  float* xf      = (float*)alloc(262144 * 4);
  float* t1      = (float*)alloc(131072 * 4);
  float* h1f     = (float*)alloc(131072 * 4);
  float* maskv   = (float*)alloc(65536 * 4);
  double* sums   = (double*)alloc(1024 * 8);
  double* sumsq  = (double*)alloc(1024 * 8);
  double* crossep = (double*)alloc(65536 * 8);
  double* crossef = (double*)alloc(65536 * 8);
  u16* w2tb      = (u16*)alloc(65536 * 2);
  float* vfrag   = (float*)alloc(131072 * 4);
  u16* wfrb      = (u16*)alloc(2097152 * 2);   // per-layer W frag-linear hi/lo (4MB)
  u16* xfrb      = (u16*)alloc(262144 * 2);    // per-layer x frag-linear hi/lo (512KB)
  int* flag      = (int*)alloc(256);
  if ((size_t)(cur - (char*)d_ws) > ws_size) return;

  // GAT-phase buffers aliased onto epw1f/efw1f (both dead after k_uv):
  u16* sT_hi = (u16*)epw1f;            // 512*1024 u16 = 1 MB
  u16* sT_lo = sT_hi + 524288;         // second 1 MB of epw1f's 2 MB
  u16* a_hib = (u16*)efw1f;            // 256*1024 u16 = 512 KB
  u16* a_lob = a_hib + 262144;         // next 512 KB of efw1f's 2 MB

  hipMemsetAsync(flag, 0, 256, stream);
  hipLaunchKernelGGL(k_detect, dim3(64), dim3(256), 0, stream, (const u16*)IN(0), flag);

  { // small vectors -> canonical f32
    VArgs va;
    auto setV = [&](int qi, int role, int dst, int n) { va.v[qi] = {IN(role), dst, n}; };
    setV(0, 2, 0, 512);       // ep_b1
    setV(1, 3, 512, 512);     // ep_g
    setV(2, 4, 1024, 512);    // ep_beta
    setV(3, 5, 1536, 512);    // ep_w2
    setV(4, 6, 2048, 1);      // ep_b2
    setV(5, 8, 2064, 512);    // ef_b1
    setV(6, 9, 2576, 512);    // ef_g
    setV(7, 10, 3088, 512);   // ef_beta
    setV(8, 12, 3600, 128);   // ef_b2
    setV(9, 14, 3728, 6144);  // gat_a_src
    setV(10, 15, 9872, 6144); // gat_a_dst
    setV(11, 16, 16016, 1536);// gat_b
    setV(12, 18, 17552, 512); // op_b1
    setV(13, 19, 18064, 512); // op_g
    setV(14, 20, 18576, 512); // op_beta
    setV(15, 22, 19088, 512); // op_b2
    hipLaunchKernelGGL(k_vec, dim3(16), dim3(256), 0, stream, va, (const int*)flag, vecf);
  }

  { // big matrices -> canonical f32
    CArgs ca;
    ca.src[0] = IN(0);  ca.dst[0] = embf;  ca.n[0] = 131072;
    ca.src[1] = IN(1);  ca.dst[1] = epw1f; ca.n[1] = 524288;
    ca.src[2] = IN(7);  ca.dst[2] = efw1f; ca.n[2] = 524288;
    ca.src[3] = IN(13); ca.dst[3] = gatWf; ca.n[3] = 3145728;
    ca.src[4] = IN(17); ca.dst[4] = opw1f; ca.n[4] = 262144;
    ca.src[5] = IN(21); ca.dst[5] = opw2f; ca.n[5] = 262144;
    ca.src[6] = IN(11); ca.dst[6] = efw2f; ca.n[6] = 65536;
    hipLaunchKernelGGL(k_cvt, dim3(2048, 7), dim3(256), 0, stream, ca, (const int*)flag);
  }
  hipLaunchKernelGGL(k_w2tb, dim3(256), dim3(256), 0, stream, efw2f, w2tb);

  hipLaunchKernelGGL(k_uv, dim3(2, 64, 4), dim3(256), 0, stream, embf, epw1f, efw1f, vecf, uvf);
  hipLaunchKernelGGL(k_vfr, dim3(512), dim3(256), 0, stream, uvf, vfrag);
  hipLaunchKernelGGL(k_stats64, dim3(1024), dim3(64), 0, stream, uvf, sums, sumsq);
  hipLaunchKernelGGL(k_cross, dim3(16, 16, 2), dim3(256), 0, stream, uvf, crossep, crossef);

  hipLaunchKernelGGL(k_ep_t, dim3(16, 16), dim3(256), 0, stream,
                     uvf, sums, sumsq, crossep, vecf, act_f, maskv);
  hipLaunchKernelGGL(k_ef, dim3(256), dim3(512), 0, stream,
                     uvf, sums, sumsq, crossef, vecf, w2tb, vfrag, ef_f);

  const float* xsrc = embf;
  for (int l = 0; l < 3; ++l) {
    hipLaunchKernelGGL(k_wfr, dim3(512), dim3(256), 0, stream,
                       gatWf + l * 1048576, wfrb);
    hipLaunchKernelGGL(k_xb, dim3(64), dim3(256), 0, stream, xsrc, xfrb);
    hipLaunchKernelGGL(k_sm, dim3(64, 8), dim3(256), 0, stream, xfrb, wfrb, sf);
    hipLaunchKernelGGL(k_ad, dim3(1024), dim3(64), 0, stream, sf, vecf, l, asf, adf);
    hipLaunchKernelGGL(k_alpha, dim3(256), dim3(256), 0, stream, asf, adf, maskv,
                       a_hib, a_lob);
    hipLaunchKernelGGL(k_st, dim3(32, 4), dim3(256), 0, stream, sf, sT_hi, sT_lo);
    float* xdst = xf + (l & 1) * 131072;
    hipLaunchKernelGGL(k_aggm, dim3(16, 8), dim3(256), 0, stream,
                       a_hib, a_lob, sT_hi, sT_lo, vecf, l, xdst);
    xsrc = xdst;
  }

  hipLaunchKernelGGL(k_op, dim3(2, 128), dim3(256), 0, stream, xsrc, opw1f, vecf + 17552, t1);
  hipLaunchKernelGGL(k_ln, dim3(256), dim3(256), 0, stream, t1, vecf, h1f);
  hipLaunchKernelGGL(k_op2, dim3(2, 128), dim3(256), 0, stream, h1f, opw2f, vecf, out_f);
}